// Round 2
// baseline (430.498 us; speedup 1.0000x reference)
//
#include <hip/hip_runtime.h>
#include <hip/hip_bf16.h>

#define N_NODES 8192
#define D_DIM   256

typedef __attribute__((ext_vector_type(8))) short short8v;   // 8 x bf16 (4 VGPR)
typedef __attribute__((ext_vector_type(4))) float f32x4;

__device__ __forceinline__ float artanh_clip(float x) {
    x = fminf(x, 1.0f - 1e-7f);
    return 0.5f * logf((1.0f + x) / (1.0f - x));
}

__device__ __forceinline__ short8v cvt8_bf16(float4 lo, float4 hi) {
    union { ushort u[8]; short8v v; } r;
    r.u[0] = __bfloat16_as_ushort(__float2bfloat16(lo.x));
    r.u[1] = __bfloat16_as_ushort(__float2bfloat16(lo.y));
    r.u[2] = __bfloat16_as_ushort(__float2bfloat16(lo.z));
    r.u[3] = __bfloat16_as_ushort(__float2bfloat16(lo.w));
    r.u[4] = __bfloat16_as_ushort(__float2bfloat16(hi.x));
    r.u[5] = __bfloat16_as_ushort(__float2bfloat16(hi.y));
    r.u[6] = __bfloat16_as_ushort(__float2bfloat16(hi.z));
    r.u[7] = __bfloat16_as_ushort(__float2bfloat16(hi.w));
    return r.v;
}

// ---------------- K0: hyp_bias = proj(expmap0(bias)), plus b2 = ||hb||^2 ----
__global__ void k0_bias(const float* __restrict__ bias, float* __restrict__ hbg) {
    __shared__ float sp[4];
    __shared__ float s_g;
    int t = threadIdx.x;
    float u = bias[t];
    float v = u * u;
    #pragma unroll
    for (int o = 1; o < 64; o <<= 1) v += __shfl_xor(v, o);
    if ((t & 63) == 0) sp[t >> 6] = v;
    __syncthreads();
    if (t == 0) {
        float s  = sp[0] + sp[1] + sp[2] + sp[3];
        float un = fmaxf(sqrtf(s), 1e-15f);
        float t1 = tanhf(un);
        s_g = (t1 > 0.996f) ? (0.996f / un) : (t1 / un);
    }
    __syncthreads();
    float hb = s_g * u;
    hbg[t] = hb;
    float v2 = hb * hb;
    #pragma unroll
    for (int o = 1; o < 64; o <<= 1) v2 += __shfl_xor(v2, o);
    if ((t & 63) == 0) sp[t >> 6] = v2;
    __syncthreads();
    if (t == 0) hbg[256] = sp[0] + sp[1] + sp[2] + sp[3];
}

// ---------------- K1: HypLinear + logmap0 -> xtT (bf16, transposed [D][N]) --
// 16 rows/block, grid 512 (2 blocks/CU). Thread t owns output dim d = t.
__global__ __launch_bounds__(256) void k1_hyplinear(
    const float* __restrict__ x, const float* __restrict__ W,
    const float* __restrict__ hbg, __hip_bfloat16* __restrict__ xtT)
{
    __shared__ __align__(16) float sx[16][260];   // x tile, then reused for mx
    __shared__ __align__(16) float sw[256][36];   // W k-chunk [d][32]
    __shared__ float s_xn[16], s_P[16], s_Q[16];
    __shared__ float s_hb[256];
    __shared__ float s_b2;

    const int t  = threadIdx.x;
    const int r0 = blockIdx.x * 16;
    const int row = t >> 4;
    const int j16 = (t & 15) * 4;

    {   // load x tile: fully coalesced (lanes contiguous 16B)
        #pragma unroll
        for (int i = 0; i < 4; i++)
            *(float4*)(&sx[row][j16 + 64 * i]) =
                *(const float4*)(x + (r0 + row) * 256 + j16 + 64 * i);
    }
    s_hb[t] = hbg[t];
    if (t == 0) s_b2 = hbg[256];
    __syncthreads();

    {   // per-row ||x||^2 (16 threads/row, strided = conflict-free)
        int r = t >> 4, j = t & 15;
        float s2 = 0.f;
        #pragma unroll
        for (int i = 0; i < 16; i++) { float v = sx[r][j + 16 * i]; s2 += v * v; }
        s2 += __shfl_xor(s2, 1); s2 += __shfl_xor(s2, 2);
        s2 += __shfl_xor(s2, 4); s2 += __shfl_xor(s2, 8);
        if (j == 0) s_xn[r] = s2;
    }

    // mx[r][t] = sum_k x[r][k] * W[t][k]   (f32, W staged in 32-wide k-chunks)
    float acc[16];
    #pragma unroll
    for (int r = 0; r < 16; r++) acc[r] = 0.f;

    for (int kc = 0; kc < 8; kc++) {
        __syncthreads();
        {   // stage W chunk: f4 grid [256][8], coalesced
            int c4 = (t & 7) * 4;
            #pragma unroll
            for (int i = 0; i < 8; i++) {
                int d = i * 32 + (t >> 3);
                *(float4*)(&sw[d][c4]) = *(const float4*)(W + d * 256 + kc * 32 + c4);
            }
        }
        __syncthreads();
        #pragma unroll
        for (int kk = 0; kk < 8; kk++) {
            float4 w4 = *(const float4*)(&sw[t][kk * 4]);
            #pragma unroll
            for (int r = 0; r < 16; r++) {
                float4 x4 = *(const float4*)(&sx[r][kc * 32 + kk * 4]);
                acc[r] = fmaf(w4.x, x4.x, acc[r]);
                acc[r] = fmaf(w4.y, x4.y, acc[r]);
                acc[r] = fmaf(w4.z, x4.z, acc[r]);
                acc[r] = fmaf(w4.w, x4.w, acc[r]);
            }
        }
    }
    __syncthreads();
    #pragma unroll
    for (int r = 0; r < 16; r++) sx[r][t] = acc[r];   // reuse sx as mx tile
    __syncthreads();

    {   // per-row sumsq(mx), dot(mx, hb) -> scalar chain -> P, Q
        int r = t >> 4, j = t & 15;
        float s2 = 0.f, dt = 0.f;
        #pragma unroll
        for (int i = 0; i < 16; i++) {
            float v = sx[r][j + 16 * i];
            s2 += v * v;
            dt += v * s_hb[j + 16 * i];
        }
        s2 += __shfl_xor(s2, 1); s2 += __shfl_xor(s2, 2);
        s2 += __shfl_xor(s2, 4); s2 += __shfl_xor(s2, 8);
        dt += __shfl_xor(dt, 1); dt += __shfl_xor(dt, 2);
        dt += __shfl_xor(dt, 4); dt += __shfl_xor(dt, 8);
        if (j == 0) {
            float b2  = s_b2;
            float xn  = fmaxf(sqrtf(s_xn[r]), 1e-15f);
            float mx2 = s2;
            float mxn = fmaxf(sqrtf(mx2), 1e-15f);
            float at = artanh_clip(xn);
            float tt = tanhf(mxn / xn * at);
            float fr = tt / mxn;
            if (tt > 0.996f) fr = 0.996f / mxn;
            float mvn = fminf(tt, 0.996f);
            float x2  = mvn * mvn;
            float xy  = fr * dt;
            float cA  = 1.0f + 2.0f * xy + b2;
            float cB  = 1.0f - x2;
            float den = fmaxf(1.0f + 2.0f * xy + x2 * b2, 1e-15f);
            float P0 = cA * fr / den;
            float Q0 = cB / den;
            float hn = sqrtf(fmaxf(P0 * P0 * mx2 + 2.0f * P0 * Q0 * dt + Q0 * Q0 * b2, 0.0f));
            hn = fmaxf(hn, 1e-15f);
            float pf  = (hn > 0.996f) ? (0.996f / hn) : 1.0f;
            float hnp = fminf(hn, 0.996f);
            float lam = artanh_clip(hnp) / hnp;
            s_P[r] = lam * pf * P0;
            s_Q[r] = lam * pf * Q0;
        }
    }
    __syncthreads();

    {   // xt[r][t] = P[r]*mx[r][t] + Q[r]*hb[t]; write transposed xtT[t][r0+r]
        float hb = s_hb[t];
        unsigned int pk[8];
        #pragma unroll
        for (int r = 0; r < 16; r += 2) {
            float a0 = s_P[r]     * acc[r]     + s_Q[r]     * hb;
            float a1 = s_P[r + 1] * acc[r + 1] + s_Q[r + 1] * hb;
            unsigned int lo = (unsigned int)__bfloat16_as_ushort(__float2bfloat16(a0));
            unsigned int hi = (unsigned int)__bfloat16_as_ushort(__float2bfloat16(a1));
            pk[r >> 1] = lo | (hi << 16);
        }
        uint4* dst = (uint4*)(xtT + t * 8192 + r0);
        dst[0] = make_uint4(pk[0], pk[1], pk[2], pk[3]);
        dst[1] = make_uint4(pk[4], pk[5], pk[6], pk[7]);
    }
}

// ---------------- K2: fused adj-copy + (adj @ xt) MFMA + hyperbolic epilogue -
// grid 256, block 512 (8 waves). BM=32, BN=256, BK=64. No LDS in K-loop:
// A-fragments loaded straight from global (f32), cvt to bf16 in-reg; wc==0
// waves emit the adj passthrough from the same registers. Raw s_barrier per
// step (no vmcnt drain) keeps wc-waves lockstep for L1 reuse.
struct Tile {
    float4 A00, A01, A10, A11;
    short8v B0, B1, B2, B3;
};

__device__ __forceinline__ void load_tile(Tile& T,
    const float* aptr0, const float* aptr1, const __hip_bfloat16* bptr, int k0)
{
    T.A00 = *(const float4*)(aptr0 + k0);
    T.A01 = *(const float4*)(aptr0 + k0 + 4);
    T.A10 = *(const float4*)(aptr1 + k0);
    T.A11 = *(const float4*)(aptr1 + k0 + 4);
    T.B0  = *(const short8v*)(bptr + k0);
    T.B1  = *(const short8v*)(bptr + 16 * 8192 + k0);
    T.B2  = *(const short8v*)(bptr + 32 * 8192 + k0);
    T.B3  = *(const short8v*)(bptr + 48 * 8192 + k0);
}

__device__ __forceinline__ void consume_tile(const Tile& T, f32x4* acc,
    bool st, float* optr0, float* optr1, int k0)
{
    if (st) {
        *(float4*)(optr0 + k0)     = T.A00;
        *(float4*)(optr0 + k0 + 4) = T.A01;
        *(float4*)(optr1 + k0)     = T.A10;
        *(float4*)(optr1 + k0 + 4) = T.A11;
    }
    short8v a0 = cvt8_bf16(T.A00, T.A01);
    short8v a1 = cvt8_bf16(T.A10, T.A11);
    acc[0] = __builtin_amdgcn_mfma_f32_16x16x32_bf16(a0, T.B0, acc[0], 0, 0, 0);
    acc[1] = __builtin_amdgcn_mfma_f32_16x16x32_bf16(a0, T.B1, acc[1], 0, 0, 0);
    acc[2] = __builtin_amdgcn_mfma_f32_16x16x32_bf16(a0, T.B2, acc[2], 0, 0, 0);
    acc[3] = __builtin_amdgcn_mfma_f32_16x16x32_bf16(a0, T.B3, acc[3], 0, 0, 0);
    acc[4] = __builtin_amdgcn_mfma_f32_16x16x32_bf16(a1, T.B0, acc[4], 0, 0, 0);
    acc[5] = __builtin_amdgcn_mfma_f32_16x16x32_bf16(a1, T.B1, acc[5], 0, 0, 0);
    acc[6] = __builtin_amdgcn_mfma_f32_16x16x32_bf16(a1, T.B2, acc[6], 0, 0, 0);
    acc[7] = __builtin_amdgcn_mfma_f32_16x16x32_bf16(a1, T.B3, acc[7], 0, 0, 0);
}

__global__ __launch_bounds__(512) void k2_agg(
    const float* __restrict__ adj,
    const __hip_bfloat16* __restrict__ xtT,
    float* __restrict__ out_h,
    float* __restrict__ out_adj)
{
    __shared__ __align__(16) float sup[32][260];
    __shared__ float sF[32];

    const int t    = threadIdx.x;
    const int lane = t & 63;
    const int wave = t >> 6;
    const int wr   = wave >> 2;   // K half within BK=64
    const int wc   = wave & 3;    // col quarter of BN=256
    const int m0   = blockIdx.x * 32;

    const int arow = lane & 15;
    const int g8   = 8 * (lane >> 4);
    const int acol = wr * 32 + g8;

    const float* aptr0 = adj + (m0 + arow) * 8192 + acol;
    const float* aptr1 = aptr0 + 16 * 8192;
    float* optr0 = out_adj + (m0 + arow) * 8192 + acol;
    float* optr1 = optr0 + 16 * 8192;
    const __hip_bfloat16* bptr = xtT + (wc * 64 + arow) * 8192 + wr * 32 + g8;
    const bool st = (wc == 0);

    f32x4 acc[8];
    #pragma unroll
    for (int i = 0; i < 8; i++) acc[i] = (f32x4){0.f, 0.f, 0.f, 0.f};

    Tile Ta, Tb;
    load_tile(Ta, aptr0, aptr1, bptr, 0);

    for (int kt = 0; kt < 128; kt += 2) {
        load_tile(Tb, aptr0, aptr1, bptr, (kt + 1) * 64);
        consume_tile(Ta, acc, st, optr0, optr1, kt * 64);
        __builtin_amdgcn_s_barrier();
        if (kt + 2 < 128)
            load_tile(Ta, aptr0, aptr1, bptr, (kt + 2) * 64);
        consume_tile(Tb, acc, st, optr0, optr1, (kt + 1) * 64);
        __builtin_amdgcn_s_barrier();
    }

    // cross-wave reduce the two K-half partials (C layout: col=lane&15, row=(lane>>4)*4+q)
    const int crow0 = 4 * (lane >> 4);
    const int ccol  = lane & 15;
    if (wr == 0) {
        #pragma unroll
        for (int mf = 0; mf < 2; mf++)
            #pragma unroll
            for (int nf = 0; nf < 4; nf++)
                #pragma unroll
                for (int q = 0; q < 4; q++)
                    sup[mf * 16 + crow0 + q][wc * 64 + nf * 16 + ccol] = acc[mf * 4 + nf][q];
    }
    __syncthreads();
    if (wr == 1) {
        #pragma unroll
        for (int mf = 0; mf < 2; mf++)
            #pragma unroll
            for (int nf = 0; nf < 4; nf++)
                #pragma unroll
                for (int q = 0; q < 4; q++)
                    sup[mf * 16 + crow0 + q][wc * 64 + nf * 16 + ccol] += acc[mf * 4 + nf][q];
    }
    __syncthreads();

    {   // per-row: sumsq(all), sumsq(relu) -> scalar chain -> F (strided reads)
        int r = t >> 4, j = t & 15;
        float s2 = 0.f, sp = 0.f;
        #pragma unroll
        for (int i = 0; i < 16; i++) {
            float vv = sup[r][j + 16 * i];
            s2 += vv * vv;
            float vp = fmaxf(vv, 0.f);
            sp += vp * vp;
        }
        s2 += __shfl_xor(s2, 1); s2 += __shfl_xor(s2, 2); s2 += __shfl_xor(s2, 4); s2 += __shfl_xor(s2, 8);
        sp += __shfl_xor(sp, 1); sp += __shfl_xor(sp, 2); sp += __shfl_xor(sp, 4); sp += __shfl_xor(sp, 8);
        if (j == 0) {
            float ns = fmaxf(sqrtf(s2), 1e-15f);
            float t1 = tanhf(ns);
            float alpha = (t1 > 0.996f) ? (0.996f / ns) : (t1 / ns);   // expmap0+proj
            float nh = fminf(t1, 0.996f);
            float beta = artanh_clip(nh) / nh;                          // logmap0
            float ba = beta * alpha;
            float nxt = fmaxf(ba * sqrtf(sp), 1e-15f);                  // ||relu(xt)||
            float t2 = tanhf(nxt);
            float delta = (t2 > 0.996f) ? (0.996f / nxt) : (t2 / nxt);  // expmap0+proj
            sF[r] = delta * ba;
        }
    }
    __syncthreads();
    {   // h[m0+r][:] = F[r] * relu(support)
        int r = t >> 4, j = t & 15;
        float F = sF[r];
        float4* dst = (float4*)(out_h + (m0 + r) * 256 + j * 16);
        #pragma unroll
        for (int i = 0; i < 4; i++) {
            float4 o;
            o.x = F * fmaxf(sup[r][j * 16 + 4 * i + 0], 0.f);
            o.y = F * fmaxf(sup[r][j * 16 + 4 * i + 1], 0.f);
            o.z = F * fmaxf(sup[r][j * 16 + 4 * i + 2], 0.f);
            o.w = F * fmaxf(sup[r][j * 16 + 4 * i + 3], 0.f);
            dst[i] = o;
        }
    }
}

extern "C" void kernel_launch(void* const* d_in, const int* in_sizes, int n_in,
                              void* d_out, int out_size, void* d_ws, size_t ws_size,
                              hipStream_t stream)
{
    const float* x    = (const float*)d_in[0];
    const float* adj  = (const float*)d_in[1];
    const float* W    = (const float*)d_in[2];
    const float* bias = (const float*)d_in[3];

    float* out_h   = (float*)d_out;
    float* out_adj = out_h + (size_t)N_NODES * D_DIM;

    __hip_bfloat16* xtT = (__hip_bfloat16*)d_ws;                       // [256][8192] bf16 = 4 MB
    float* hbg = (float*)((char*)d_ws + (size_t)D_DIM * N_NODES * 2);  // hb[256] + b2

    k0_bias<<<1, 256, 0, stream>>>(bias, hbg);
    k1_hyplinear<<<512, 256, 0, stream>>>(x, W, hbg, xtT);
    k2_agg<<<256, 512, 0, stream>>>(adj, xtT, out_h, out_adj);
}

// Round 3
// 304.759 us; speedup vs baseline: 1.4126x; 1.4126x over previous
//
#include <hip/hip_runtime.h>
#include <hip/hip_bf16.h>

#define N_NODES 8192
#define D_DIM   256

typedef __attribute__((ext_vector_type(8))) short short8v;   // 8 x bf16 (4 VGPR)
typedef __attribute__((ext_vector_type(4))) float f32x4;

__device__ __forceinline__ float artanh_clip(float x) {
    x = fminf(x, 1.0f - 1e-7f);
    return 0.5f * logf((1.0f + x) / (1.0f - x));
}

__device__ __forceinline__ ushort4 cvt4_bf16(float4 v) {
    ushort4 b;
    b.x = __bfloat16_as_ushort(__float2bfloat16(v.x));
    b.y = __bfloat16_as_ushort(__float2bfloat16(v.y));
    b.z = __bfloat16_as_ushort(__float2bfloat16(v.z));
    b.w = __bfloat16_as_ushort(__float2bfloat16(v.w));
    return b;
}

// ---------------- K0: hyp_bias = proj(expmap0(bias)), plus b2 = ||hb||^2 ----
__global__ void k0_bias(const float* __restrict__ bias, float* __restrict__ hbg) {
    __shared__ float sp[4];
    __shared__ float s_g;
    int t = threadIdx.x;
    float u = bias[t];
    float v = u * u;
    #pragma unroll
    for (int o = 1; o < 64; o <<= 1) v += __shfl_xor(v, o);
    if ((t & 63) == 0) sp[t >> 6] = v;
    __syncthreads();
    if (t == 0) {
        float s  = sp[0] + sp[1] + sp[2] + sp[3];
        float un = fmaxf(sqrtf(s), 1e-15f);
        float t1 = tanhf(un);
        s_g = (t1 > 0.996f) ? (0.996f / un) : (t1 / un);
    }
    __syncthreads();
    float hb = s_g * u;
    hbg[t] = hb;
    float v2 = hb * hb;
    #pragma unroll
    for (int o = 1; o < 64; o <<= 1) v2 += __shfl_xor(v2, o);
    if ((t & 63) == 0) sp[t >> 6] = v2;
    __syncthreads();
    if (t == 0) hbg[256] = sp[0] + sp[1] + sp[2] + sp[3];
}

// ---------------- K1: HypLinear + logmap0 -> xtT (bf16, transposed [D][N]) --
// 16 rows/block, grid 512. x is read via WAVE-UNIFORM addresses (no threadIdx
// in the index) -> compiler scalarizes to s_load; FMA uses SGPR operand.
// W staged in LDS (coalesced), 1 ds_read_b128 per 4 k per thread.
__global__ __launch_bounds__(256) void k1_hyplinear(
    const float* __restrict__ x, const float* __restrict__ W,
    const float* __restrict__ hbg, __hip_bfloat16* __restrict__ xtT)
{
    __shared__ __align__(16) float sw[256][36];   // W k-chunk [d][32]
    __shared__ __align__(16) float smx[16][260];  // mx tile for norm pass
    __shared__ float s_xn[16], s_P[16], s_Q[16];
    __shared__ float s_hb[256];
    __shared__ float s_b2;

    const int t  = threadIdx.x;
    const int r0 = blockIdx.x * 16;

    s_hb[t] = hbg[t];
    if (t == 0) s_b2 = hbg[256];

    {   // per-row ||x||^2 : 16 threads/row, thread reads 16 consecutive floats
        int r = t >> 4, j = t & 15;
        const float* xp = x + (r0 + r) * 256 + j * 16;
        float s2 = 0.f;
        #pragma unroll
        for (int i = 0; i < 4; i++) {
            float4 v = *(const float4*)(xp + 4 * i);
            s2 += v.x * v.x + v.y * v.y + v.z * v.z + v.w * v.w;
        }
        s2 += __shfl_xor(s2, 1); s2 += __shfl_xor(s2, 2);
        s2 += __shfl_xor(s2, 4); s2 += __shfl_xor(s2, 8);
        if (j == 0) s_xn[r] = s2;
    }

    float acc[16];
    #pragma unroll
    for (int r = 0; r < 16; r++) acc[r] = 0.f;

    for (int kc = 0; kc < 8; kc++) {
        __syncthreads();
        {   // stage W chunk [256][32], coalesced
            int c4 = (t & 7) * 4;
            #pragma unroll
            for (int i = 0; i < 8; i++) {
                int d = i * 32 + (t >> 3);
                *(float4*)(&sw[d][c4]) = *(const float4*)(W + d * 256 + kc * 32 + c4);
            }
        }
        __syncthreads();
        #pragma unroll
        for (int kk = 0; kk < 8; kk++) {
            float4 w4 = *(const float4*)(&sw[t][kk * 4]);
            #pragma unroll
            for (int r = 0; r < 16; r++) {
                // uniform address (no threadIdx) -> s_load, SGPR operands
                const float4 xv = *(const float4*)(x + (r0 + r) * 256 + kc * 32 + kk * 4);
                acc[r] = fmaf(xv.x, w4.x, acc[r]);
                acc[r] = fmaf(xv.y, w4.y, acc[r]);
                acc[r] = fmaf(xv.z, w4.z, acc[r]);
                acc[r] = fmaf(xv.w, w4.w, acc[r]);
            }
        }
    }
    __syncthreads();
    #pragma unroll
    for (int r = 0; r < 16; r++) smx[r][t] = acc[r];
    __syncthreads();

    {   // per-row sumsq(mx), dot(mx, hb) -> scalar chain -> P, Q
        int r = t >> 4, j = t & 15;
        float s2 = 0.f, dt = 0.f;
        #pragma unroll
        for (int i = 0; i < 16; i++) {
            float v = smx[r][j + 16 * i];
            s2 += v * v;
            dt += v * s_hb[j + 16 * i];
        }
        s2 += __shfl_xor(s2, 1); s2 += __shfl_xor(s2, 2);
        s2 += __shfl_xor(s2, 4); s2 += __shfl_xor(s2, 8);
        dt += __shfl_xor(dt, 1); dt += __shfl_xor(dt, 2);
        dt += __shfl_xor(dt, 4); dt += __shfl_xor(dt, 8);
        if (j == 0) {
            float b2  = s_b2;
            float xn  = fmaxf(sqrtf(s_xn[r]), 1e-15f);
            float mx2 = s2;
            float mxn = fmaxf(sqrtf(mx2), 1e-15f);
            float at = artanh_clip(xn);
            float tt = tanhf(mxn / xn * at);
            float fr = tt / mxn;
            if (tt > 0.996f) fr = 0.996f / mxn;
            float mvn = fminf(tt, 0.996f);
            float x2  = mvn * mvn;
            float xy  = fr * dt;
            float cA  = 1.0f + 2.0f * xy + b2;
            float cB  = 1.0f - x2;
            float den = fmaxf(1.0f + 2.0f * xy + x2 * b2, 1e-15f);
            float P0 = cA * fr / den;
            float Q0 = cB / den;
            float hn = sqrtf(fmaxf(P0 * P0 * mx2 + 2.0f * P0 * Q0 * dt + Q0 * Q0 * b2, 0.0f));
            hn = fmaxf(hn, 1e-15f);
            float pf  = (hn > 0.996f) ? (0.996f / hn) : 1.0f;
            float hnp = fminf(hn, 0.996f);
            float lam = artanh_clip(hnp) / hnp;
            s_P[r] = lam * pf * P0;
            s_Q[r] = lam * pf * Q0;
        }
    }
    __syncthreads();

    {   // xt[r][t] = P[r]*mx[r][t] + Q[r]*hb[t]; write transposed xtT[t][r0+r]
        float hb = s_hb[t];
        unsigned int pk[8];
        #pragma unroll
        for (int r = 0; r < 16; r += 2) {
            float a0 = s_P[r]     * acc[r]     + s_Q[r]     * hb;
            float a1 = s_P[r + 1] * acc[r + 1] + s_Q[r + 1] * hb;
            unsigned int lo = (unsigned int)__bfloat16_as_ushort(__float2bfloat16(a0));
            unsigned int hi = (unsigned int)__bfloat16_as_ushort(__float2bfloat16(a1));
            pk[r >> 1] = lo | (hi << 16);
        }
        uint4* dst = (uint4*)(xtT + t * 8192 + r0);
        dst[0] = make_uint4(pk[0], pk[1], pk[2], pk[3]);
        dst[1] = make_uint4(pk[4], pk[5], pk[6], pk[7]);
    }
}

// ---------------- K2: split-K fused adj-copy + (adj @ xt) MFMA -> atomic acc -
// grid 1024 (4 blocks/CU): block bx: mtile = bx>>2 (BM=32), slab = bx&3
// (K-range 2048 = 32 steps of BK=64). LDS = A dbuf only (9.2 KB). Waves:
// wr = K-half, wc = col quarter. Partials atomicAdd'ed into out_h (pre-zeroed).
__global__ __launch_bounds__(512) void k2_agg(
    const float* __restrict__ adj,
    const __hip_bfloat16* __restrict__ xtT,
    float* __restrict__ out_h,
    float* __restrict__ out_adj)
{
    __shared__ __align__(16) __hip_bfloat16 As[2][32][72];

    const int t     = threadIdx.x;
    const int lane  = t & 63;
    const int wave  = t >> 6;
    const int wr    = wave >> 2;
    const int wc    = wave & 3;
    const int bx    = blockIdx.x;
    const int m0    = (bx >> 2) * 32;
    const int kbase = (bx & 3) * 2048;

    const int srow = t >> 4;
    const int scol = (t & 15) * 4;
    const float* astage = adj     + (m0 + srow) * 8192 + kbase + scol;
    float*       ostage = out_adj + (m0 + srow) * 8192 + kbase + scol;

    const int arow = lane & 15;
    const int g8   = 8 * (lane >> 4);
    const int acol = wr * 32 + g8;
    const __hip_bfloat16* bptr = xtT + (wc * 64 + arow) * 8192 + kbase + wr * 32 + g8;

    f32x4 acc[8];
    #pragma unroll
    for (int i = 0; i < 8; i++) acc[i] = (f32x4){0.f, 0.f, 0.f, 0.f};

    {   // prologue: stage tile 0 + adj passthrough
        float4 v = *(const float4*)(astage);
        *(float4*)(ostage) = v;
        *(ushort4*)(&As[0][srow][scol]) = cvt4_bf16(v);
    }
    __syncthreads();

    for (int kt = 0; kt < 32; kt++) {
        const int cur = kt & 1;
        const bool hn = (kt + 1 < 32);
        float4 v;
        if (hn) v = *(const float4*)(astage + (kt + 1) * 64);   // issue early

        const __hip_bfloat16* bb = bptr + kt * 64;
        short8v b0 = *(const short8v*)(bb);
        short8v b1 = *(const short8v*)(bb + 16 * 8192);
        short8v b2 = *(const short8v*)(bb + 32 * 8192);
        short8v b3 = *(const short8v*)(bb + 48 * 8192);
        short8v a0 = *(const short8v*)(&As[cur][arow][acol]);
        short8v a1 = *(const short8v*)(&As[cur][16 + arow][acol]);

        acc[0] = __builtin_amdgcn_mfma_f32_16x16x32_bf16(a0, b0, acc[0], 0, 0, 0);
        acc[1] = __builtin_amdgcn_mfma_f32_16x16x32_bf16(a0, b1, acc[1], 0, 0, 0);
        acc[2] = __builtin_amdgcn_mfma_f32_16x16x32_bf16(a0, b2, acc[2], 0, 0, 0);
        acc[3] = __builtin_amdgcn_mfma_f32_16x16x32_bf16(a0, b3, acc[3], 0, 0, 0);
        acc[4] = __builtin_amdgcn_mfma_f32_16x16x32_bf16(a1, b0, acc[4], 0, 0, 0);
        acc[5] = __builtin_amdgcn_mfma_f32_16x16x32_bf16(a1, b1, acc[5], 0, 0, 0);
        acc[6] = __builtin_amdgcn_mfma_f32_16x16x32_bf16(a1, b2, acc[6], 0, 0, 0);
        acc[7] = __builtin_amdgcn_mfma_f32_16x16x32_bf16(a1, b3, acc[7], 0, 0, 0);

        if (hn) {   // write-late: passthrough + next LDS buffer
            *(float4*)(ostage + (kt + 1) * 64) = v;
            *(ushort4*)(&As[cur ^ 1][srow][scol]) = cvt4_bf16(v);
        }
        __syncthreads();
    }

    // atomic accumulate partials (C layout: col=lane&15, row=(lane>>4)*4+q)
    const int crow0 = 4 * (lane >> 4);
    const int ccol  = lane & 15;
    #pragma unroll
    for (int mf = 0; mf < 2; mf++)
        #pragma unroll
        for (int nf = 0; nf < 4; nf++)
            #pragma unroll
            for (int q = 0; q < 4; q++)
                atomicAdd(out_h + (m0 + mf * 16 + crow0 + q) * 256 + wc * 64 + nf * 16 + ccol,
                          acc[mf * 4 + nf][q]);
}

// ---------------- K3: in-place epilogue on support (out_h) -------------------
// 16 rows/block, 16 threads/row; butterfly shfl gives all lanes the row sums.
__global__ __launch_bounds__(256) void k3_epilogue(float* __restrict__ h) {
    const int t = threadIdx.x;
    const int r = blockIdx.x * 16 + (t >> 4);
    const int j = t & 15;
    float* p = h + r * 256 + j * 16;

    float4 v[4];
    float s2 = 0.f, sp = 0.f;
    #pragma unroll
    for (int i = 0; i < 4; i++) {
        v[i] = *(const float4*)(p + 4 * i);
        s2 += v[i].x * v[i].x + v[i].y * v[i].y + v[i].z * v[i].z + v[i].w * v[i].w;
        float px = fmaxf(v[i].x, 0.f), py = fmaxf(v[i].y, 0.f);
        float pz = fmaxf(v[i].z, 0.f), pw = fmaxf(v[i].w, 0.f);
        sp += px * px + py * py + pz * pz + pw * pw;
    }
    s2 += __shfl_xor(s2, 1); s2 += __shfl_xor(s2, 2); s2 += __shfl_xor(s2, 4); s2 += __shfl_xor(s2, 8);
    sp += __shfl_xor(sp, 1); sp += __shfl_xor(sp, 2); sp += __shfl_xor(sp, 4); sp += __shfl_xor(sp, 8);

    float ns = fmaxf(sqrtf(s2), 1e-15f);
    float t1 = tanhf(ns);
    float alpha = (t1 > 0.996f) ? (0.996f / ns) : (t1 / ns);   // expmap0+proj
    float nh = fminf(t1, 0.996f);
    float beta = artanh_clip(nh) / nh;                          // logmap0
    float ba = beta * alpha;
    float nxt = fmaxf(ba * sqrtf(sp), 1e-15f);                  // ||relu(xt)||
    float t2 = tanhf(nxt);
    float delta = (t2 > 0.996f) ? (0.996f / nxt) : (t2 / nxt);  // expmap0+proj
    float F = delta * ba;

    #pragma unroll
    for (int i = 0; i < 4; i++) {
        float4 o;
        o.x = F * fmaxf(v[i].x, 0.f);
        o.y = F * fmaxf(v[i].y, 0.f);
        o.z = F * fmaxf(v[i].z, 0.f);
        o.w = F * fmaxf(v[i].w, 0.f);
        *(float4*)(p + 4 * i) = o;
    }
}

extern "C" void kernel_launch(void* const* d_in, const int* in_sizes, int n_in,
                              void* d_out, int out_size, void* d_ws, size_t ws_size,
                              hipStream_t stream)
{
    const float* x    = (const float*)d_in[0];
    const float* adj  = (const float*)d_in[1];
    const float* W    = (const float*)d_in[2];
    const float* bias = (const float*)d_in[3];

    float* out_h   = (float*)d_out;
    float* out_adj = out_h + (size_t)N_NODES * D_DIM;

    __hip_bfloat16* xtT = (__hip_bfloat16*)d_ws;                       // [256][8192] bf16 = 4 MB
    float* hbg = (float*)((char*)d_ws + (size_t)D_DIM * N_NODES * 2);  // hb[256] + b2

    k0_bias<<<1, 256, 0, stream>>>(bias, hbg);
    k1_hyplinear<<<512, 256, 0, stream>>>(x, W, hbg, xtT);
    hipMemsetAsync(out_h, 0, (size_t)N_NODES * D_DIM * sizeof(float), stream);
    k2_agg<<<1024, 512, 0, stream>>>(adj, xtT, out_h, out_adj);
    k3_epilogue<<<512, 256, 0, stream>>>(out_h);
}